// Round 4
// baseline (71.058 us; speedup 1.0000x reference)
//
#include <hip/hip_runtime.h>
#include <math.h>

// GLVQ via bf16 MFMA. Prep: proto fp32 -> bf16, XOR-swizzled layout + psq + zero out.
// Main: async global_load_lds proto staging, swizzled conflict-free LDS, fused epilogue.
#define N_ROWS  8192
#define DIM     256
#define NPROTO  128
#define ROWS_PB 16
#define NBLK    (N_ROWS / ROWS_PB)  // 512 blocks -> 2 blocks/CU

typedef float f32x4 __attribute__((ext_vector_type(4)));
typedef short s16x8 __attribute__((ext_vector_type(8)));

__device__ __forceinline__ unsigned short f2bf(float f) {
  unsigned int u = __float_as_uint(f);
  u += 0x7fffu + ((u >> 16) & 1u);
  return (unsigned short)(u >> 16);
}

__device__ __forceinline__ void gl_lds16(const void* g, void* l) {
  // async 16B/lane global->LDS DMA; LDS dst must be wave-uniform base + lane*16
  __builtin_amdgcn_global_load_lds(
      (const __attribute__((address_space(1))) void*)g,
      (__attribute__((address_space(3))) void*)l, 16, 0, 0);
}

// ---- prep: 16 blocks x 256 threads; thread owns one 8-elem chunk of one proto row.
// Writes bf16 chunk to SWIZZLED slot (row*32 + (chunk ^ (row&7))) so the main kernel
// can DMA-copy verbatim and still get bank-balanced b128 reads. Also psq + out=0.
__global__ __launch_bounds__(256) void glvq_prep_kernel(
    const float* __restrict__ proto, unsigned short* __restrict__ pbf,
    float* __restrict__ psq, float* __restrict__ out) {
  const int tid = blockIdx.x * 256 + threadIdx.x;  // 0..4095
  const int row = tid >> 5;
  const int co  = tid & 31;
  const float4* p4 = (const float4*)proto;
  float4 a = p4[tid * 2];
  float4 b = p4[tid * 2 + 1];
  union { s16x8 v; unsigned short u[8]; } pk;
  pk.u[0] = f2bf(a.x); pk.u[1] = f2bf(a.y); pk.u[2] = f2bf(a.z); pk.u[3] = f2bf(a.w);
  pk.u[4] = f2bf(b.x); pk.u[5] = f2bf(b.y); pk.u[6] = f2bf(b.z); pk.u[7] = f2bf(b.w);
  const int slot = row * 32 + (co ^ (row & 7));
  *(s16x8*)&pbf[slot * 8] = pk.v;
  float s = a.x * a.x + a.y * a.y + a.z * a.z + a.w * a.w +
            b.x * b.x + b.y * b.y + b.z * b.z + b.w * b.w;
#pragma unroll
  for (int m = 1; m <= 16; m <<= 1) s += __shfl_xor(s, m);  // 32-lane row reduce
  if (co == 0) psq[row] = s;
  if (tid == 0) out[0] = 0.f;
}

// ---- main: 512 blocks x 256 threads, 16 rows/block ----
__global__ __launch_bounds__(256, 2) void glvq_kernel(
    const float* __restrict__ x, const int* __restrict__ y,
    const unsigned short* __restrict__ pbf, const float* __restrict__ psq_g,
    float* __restrict__ out) {
  __shared__ unsigned short pT[NPROTO * 256];   // 65536 B, swizzled bf16 protos
  __shared__ unsigned short xT[ROWS_PB * 256];  // 8192 B, swizzled bf16 x-tile
  __shared__ float psq[NPROTO];
  __shared__ float xsq[ROWS_PB];
  __shared__ int   ylds[ROWS_PB];
  __shared__ float red1[4 * ROWS_PB];
  __shared__ float red2[4 * ROWS_PB];

  const int t = threadIdx.x;
  const int r0 = blockIdx.x * ROWS_PB;

  // phase 1a: async DMA protos (verbatim copy of pre-swizzled layout), 16 x 16B/lane
#pragma unroll
  for (int j = 0; j < 16; ++j) {
    int c = j * 256 + t;  // 16B chunk index, 0..4095
    gl_lds16((const char*)pbf + (size_t)c * 16, (char*)pT + (size_t)c * 16);
  }
  if (t < NPROTO) psq[t] = psq_g[t];
  if (t < ROWS_PB) ylds[t] = y[r0 + t];

  // phase 1b: x fp32 -> bf16 swizzled LDS + exact xsq (overlaps the DMA)
  {
    const int r = t >> 4, i = t & 15;
    const float4* xr = (const float4*)x + (size_t)(r0 + r) * 64 + i * 4;
    float4 v0 = xr[0], v1 = xr[1], v2 = xr[2], v3 = xr[3];
    union { s16x8 v; unsigned short u[8]; } pk0, pk1;
    pk0.u[0] = f2bf(v0.x); pk0.u[1] = f2bf(v0.y); pk0.u[2] = f2bf(v0.z); pk0.u[3] = f2bf(v0.w);
    pk0.u[4] = f2bf(v1.x); pk0.u[5] = f2bf(v1.y); pk0.u[6] = f2bf(v1.z); pk0.u[7] = f2bf(v1.w);
    pk1.u[0] = f2bf(v2.x); pk1.u[1] = f2bf(v2.y); pk1.u[2] = f2bf(v2.z); pk1.u[3] = f2bf(v2.w);
    pk1.u[4] = f2bf(v3.x); pk1.u[5] = f2bf(v3.y); pk1.u[6] = f2bf(v3.z); pk1.u[7] = f2bf(v3.w);
    const int r7 = r & 7;
    *(s16x8*)&xT[(r * 32 + ((2 * i) ^ r7)) * 8] = pk0.v;
    *(s16x8*)&xT[(r * 32 + ((2 * i + 1) ^ r7)) * 8] = pk1.v;
    float s = v0.x * v0.x + v0.y * v0.y + v0.z * v0.z + v0.w * v0.w +
              v1.x * v1.x + v1.y * v1.y + v1.z * v1.z + v1.w * v1.w +
              v2.x * v2.x + v2.y * v2.y + v2.z * v2.z + v2.w * v2.w +
              v3.x * v3.x + v3.y * v3.y + v3.z * v3.z + v3.w * v3.w;
#pragma unroll
    for (int m = 1; m <= 8; m <<= 1) s += __shfl_xor(s, m);
    if (i == 0) xsq[r] = s;
  }
  __syncthreads();  // drains DMA (vmcnt) + ds_writes (lgkmcnt)

  // phase 2: wave w -> protos [w*32, +32), 16 rows, K=256; swizzled b128 reads
  const int l = t & 63;
  const int w = t >> 6;
  const int mq = l >> 4;
  const int mc = l & 15;
  const int m7 = mc & 7;
  f32x4 acc0 = {0.f, 0.f, 0.f, 0.f};
  f32x4 acc1 = {0.f, 0.f, 0.f, 0.f};
  const unsigned short* xbase = &xT[mc * 256];
  const unsigned short* b0p = &pT[(w * 32 + mc) * 256];
  const unsigned short* b1p = b0p + 16 * 256;
#pragma unroll
  for (int ks = 0; ks < 8; ++ks) {
    const int off = ((mq + 4 * ks) ^ m7) * 8;  // swizzled 8-elem chunk offset
    s16x8 af  = *(const s16x8*)(xbase + off);
    s16x8 bf0 = *(const s16x8*)(b0p + off);
    s16x8 bf1 = *(const s16x8*)(b1p + off);
    acc0 = __builtin_amdgcn_mfma_f32_16x16x32_bf16(af, bf0, acc0, 0, 0, 0);
    acc1 = __builtin_amdgcn_mfma_f32_16x16x32_bf16(af, bf1, acc1, 0, 0, 0);
  }

  // phase 3: dist = xsq + psq - 2*dot; d1/d2; 16-lane min reduce
  // C/D layout (m89): col = lane&15 (proto), row = (lane>>4)*4 + reg (x-row)
  const int p0i = w * 32 + mc;
  const int p1i = p0i + 16;
  const float pq0 = psq[p0i];
  const float pq1 = psq[p1i];
  float r1[4], r2[4];
#pragma unroll
  for (int reg = 0; reg < 4; ++reg) {
    int m = mq * 4 + reg;
    float xs = xsq[m];
    int ym = ylds[m];
    float d0 = xs + pq0 - 2.f * acc0[reg];
    float d1_ = xs + pq1 - 2.f * acc1[reg];
    float dd1 = 1e30f, dd2 = 1e30f;
    if (p0i == ym) dd1 = d0; else dd2 = d0;
    if (p1i == ym) dd1 = fminf(dd1, d1_); else dd2 = fminf(dd2, d1_);
    r1[reg] = dd1;
    r2[reg] = dd2;
  }
#pragma unroll
  for (int m = 1; m <= 8; m <<= 1) {
#pragma unroll
    for (int reg = 0; reg < 4; ++reg) {
      r1[reg] = fminf(r1[reg], __shfl_xor(r1[reg], m));
      r2[reg] = fminf(r2[reg], __shfl_xor(r2[reg], m));
    }
  }
  if (mc == 0) {
#pragma unroll
    for (int reg = 0; reg < 4; ++reg) {
      red1[w * ROWS_PB + mq * 4 + reg] = r1[reg];
      red2[w * ROWS_PB + mq * 4 + reg] = r2[reg];
    }
  }
  __syncthreads();

  // phase 4: combine waves, sigmoid, block sum, one atomic
  if (t < ROWS_PB) {
    float d1 = 1e30f, d2 = 1e30f;
#pragma unroll
    for (int wv = 0; wv < 4; ++wv) {
      d1 = fminf(d1, red1[wv * ROWS_PB + t]);
      d2 = fminf(d2, red2[wv * ROWS_PB + t]);
    }
    float mu = (d1 - d2) / (d1 + d2);
    float s = 1.f / (1.f + __expf(mu));  // sigmoid(-mu)
#pragma unroll
    for (int m = 1; m <= 8; m <<= 1) s += __shfl_xor(s, m);  // lanes 0..15
    if (t == 0) atomicAdd(out, s * (1.f / (float)N_ROWS));
  }
}

extern "C" void kernel_launch(void* const* d_in, const int* in_sizes, int n_in,
                              void* d_out, int out_size, void* d_ws, size_t ws_size,
                              hipStream_t stream) {
  const float* x = (const float*)d_in[0];       // [8192, 256] fp32
  const int* y = (const int*)d_in[1];           // [8192] int32
  const float* proto = (const float*)d_in[2];   // [128, 256] fp32
  float* out = (float*)d_out;                   // scalar fp32

  unsigned short* pbf = (unsigned short*)d_ws;             // 64 KB swizzled bf16 protos
  float* psq = (float*)((char*)d_ws + NPROTO * DIM * 2);   // 512 B psq

  glvq_prep_kernel<<<16, 256, 0, stream>>>(proto, pbf, psq, out);
  glvq_kernel<<<NBLK, 256, 0, stream>>>(x, y, pbf, psq, out);
}